// Round 16
// baseline (42.530 us; speedup 1.0000x reference)
//
#include <hip/hip_runtime.h>

#define B_SZ 1024
#define F_SZ 512
#define NK   50
#define KD   5
#define C_SZ 250              // NK*KD
#define OUTW 562              // F_SZ + NK
#define PLANE (C_SZ * B_SZ)   // SoA M plane: [col c=k*5+d][row], 256000 floats
#define TILE 64
#define LOG2E 1.44269504088896340736f

// ---------------------------------------------------------------------------
// K1: fused GEMM + copy (round-9 version — measured best). grid 384 x 256.
//  blocks [0,256):   M = x@T scaled by log2e, SoA planes ws2[ks][c][row].
//                    rt = blk&127 (8 rows), ks = blk>>7 (256 f each).
//                    64 MB total T re-reads (L2/L3); x block-uniform -> s_load.
//  blocks [256,384): copy x rows into out (float2), 8 rows/block.
// ---------------------------------------------------------------------------
__global__ __launch_bounds__(256) void gemm_copy_kernel(const float* __restrict__ x,
                                                        const float* __restrict__ T,
                                                        float* __restrict__ ws2,
                                                        float* __restrict__ out) {
    const int t = threadIdx.x;

    if (blockIdx.x >= 256) {                 // ---- copy path
        const int b = blockIdx.x - 256;      // 0..127
#pragma unroll
        for (int r = 0; r < 8; ++r) {
            const int row = b * 8 + r;
            const float2* src = (const float2*)(x + (size_t)row * F_SZ);
            float2* dst = (float2*)(out + (size_t)row * OUTW);
            dst[t] = src[t];
        }
        return;
    }

    // ---- gemm path
    const int rt = blockIdx.x & 127;         // 8-row tile
    const int ks = blockIdx.x >> 7;          // k-split (0,1)
    if (t >= C_SZ) return;                   // no __syncthreads in this path
    const int r0 = rt * 8;
    const int f0 = ks * 256;

    float acc[8] = {0.f, 0.f, 0.f, 0.f, 0.f, 0.f, 0.f, 0.f};
    const float* xp = x + (size_t)r0 * F_SZ + f0;     // block-uniform base
    const float* Tp = T + (size_t)f0 * C_SZ + t;

#pragma unroll 8
    for (int f = 0; f < 256; ++f) {
        const float tv = Tp[(size_t)f * C_SZ];
#pragma unroll
        for (int r = 0; r < 8; ++r)
            acc[r] += xp[r * F_SZ + f] * tv;          // uniform -> s_load
    }

    float* dst = ws2 + ((size_t)(ks * C_SZ + t)) * B_SZ + r0;   // 32B aligned
    float4 lo = make_float4(acc[0] * LOG2E, acc[1] * LOG2E,
                            acc[2] * LOG2E, acc[3] * LOG2E);
    float4 hi = make_float4(acc[4] * LOG2E, acc[5] * LOG2E,
                            acc[6] * LOG2E, acc[7] * LOG2E);
    ((float4*)dst)[0] = lo;
    ((float4*)dst)[1] = hi;
}

// ---------------------------------------------------------------------------
// K2: pairwise features, SINGLE-WRITER direct-output (rounds 9/13/14 lesson:
// three different pair structures all hit ~36us -> the schedule (3 nodes +
// partials + reduce) was the wall, not pair's inner loop).
// grid 800 = 50 k x 16 row-strips of 64; 256 threads (4 waves).
//   - stage q[5][1024] = plane0+plane1 for this k (20KB LDS, coalesced f4).
//   - thread (r = t&31, jq = t>>5): rows {bi+r, bi+r+32}, j in [jq*128,+128).
//     R=2 rows amortize each broadcast c-vector; per 4-j chunk: 5 ds_read_b128
//     (2 addr/wave -> conflict-free broadcast) + 8 pairs x 11 VALU.
//   - rowp[8][64] partials; t<64 folds 8 and writes out[(bi+t)*562+512+k]
//     EXACTLY ONCE: no atomics, no partial buffer, no reduce kernel, no
//     pre-zero of feature columns. 2 graph nodes total.
// ---------------------------------------------------------------------------
__global__ __launch_bounds__(256) void pair_kernel(const float* __restrict__ ws2,
                                                   float* __restrict__ out) {
    const int k  = blockIdx.x >> 4;          // 0..49
    const int ti = blockIdx.x & 15;          // row-strip
    const int t  = threadIdx.x;
    const int r  = t & 31;
    const int jq = t >> 5;                   // 0..7

    __shared__ __align__(16) float q[KD][B_SZ];   // 20 KB summed M for this k
    __shared__ float rowp[8][TILE];               // 2 KB

    const float* pa = ws2 + (size_t)k * (KD * B_SZ);   // plane 0, cols k*5..
    const float* pb = pa + (size_t)PLANE;              // plane 1

    {   // stage q = pa + pb: 1280 float4 across 256 threads (5 each), coalesced
        const float4* A = (const float4*)pa;
        const float4* B = (const float4*)pb;
        float4* Q = (float4*)&q[0][0];
#pragma unroll
        for (int i = 0; i < 5; ++i) {
            const int idx = i * 256 + t;     // row i, cols 4t..4t+3
            const float4 a = A[idx];
            const float4 b = B[idx];
            Q[idx] = make_float4(a.x + b.x, a.y + b.y, a.z + b.z, a.w + b.w);
        }
    }
    __syncthreads();

    const int bi = ti * TILE;
    float mi0[KD], mi1[KD];                  // this thread's two rows
#pragma unroll
    for (int d = 0; d < KD; ++d) {
        mi0[d] = q[d][bi + r];
        mi1[d] = q[d][bi + r + 32];
    }

    float acc0 = 0.0f, acc1 = 0.0f;
    const int jb = jq * 128;
#pragma unroll 4
    for (int ch = 0; ch < 32; ++ch) {
        const int j0 = jb + ch * 4;
        const float4 c0 = *(const float4*)&q[0][j0];   // broadcast b128 (2 addr/wave)
        const float4 c1 = *(const float4*)&q[1][j0];
        const float4 c2 = *(const float4*)&q[2][j0];
        const float4 c3 = *(const float4*)&q[3][j0];
        const float4 c4 = *(const float4*)&q[4][j0];
#define PAIR_ONE(C)                                                              \
        {                                                                        \
            const float s0 = __builtin_fabsf(mi0[0] - c0.C)                      \
                           + __builtin_fabsf(mi0[1] - c1.C)                      \
                           + __builtin_fabsf(mi0[2] - c2.C)                      \
                           + __builtin_fabsf(mi0[3] - c3.C)                      \
                           + __builtin_fabsf(mi0[4] - c4.C);                     \
            const float s1 = __builtin_fabsf(mi1[0] - c0.C)                      \
                           + __builtin_fabsf(mi1[1] - c1.C)                      \
                           + __builtin_fabsf(mi1[2] - c2.C)                      \
                           + __builtin_fabsf(mi1[3] - c3.C)                      \
                           + __builtin_fabsf(mi1[4] - c4.C);                     \
            acc0 += __builtin_amdgcn_exp2f(-s0);                                 \
            acc1 += __builtin_amdgcn_exp2f(-s1);                                 \
        }
        PAIR_ONE(x) PAIR_ONE(y) PAIR_ONE(z) PAIR_ONE(w)
#undef PAIR_ONE
    }

    rowp[jq][r]      = acc0;                 // (jq, r) unique -> no collision
    rowp[jq][r + 32] = acc1;
    __syncthreads();

    if (t < TILE) {                          // fold 8 j-range partials, write once
        const float s = rowp[0][t] + rowp[1][t] + rowp[2][t] + rowp[3][t]
                      + rowp[4][t] + rowp[5][t] + rowp[6][t] + rowp[7][t];
        out[(size_t)(bi + t) * OUTW + F_SZ + k] = s;
    }
}

// ---------------------------------------------------------------------------
extern "C" void kernel_launch(void* const* d_in, const int* in_sizes, int n_in,
                              void* d_out, int out_size, void* d_ws, size_t ws_size,
                              hipStream_t stream) {
    const float* x = (const float*)d_in[0];   // [1024, 512]
    const float* T = (const float*)d_in[1];   // [512, 250]
    float* out = (float*)d_out;               // [1024, 562]
    float* ws2 = (float*)d_ws;                // 2 SoA planes [250][1024] = 2.05 MB

    gemm_copy_kernel<<<384, 256, 0, stream>>>(x, T, ws2, out);
    pair_kernel<<<NK * 16, 256, 0, stream>>>(ws2, out);
}

// Round 17
// 34.492 us; speedup vs baseline: 1.2330x; 1.2330x over previous
//
#include <hip/hip_runtime.h>

#define B_SZ 1024
#define F_SZ 512
#define NK   50
#define KD   5
#define C_SZ 250              // NK*KD
#define OUTW 562              // F_SZ + NK
#define PLANE (C_SZ * B_SZ)   // SoA M plane: [col c=k*5+d][row], 256000 floats
#define KS   4                // k-splits (gemm occupancy: 512 blocks, 2.5/CU)
#define NT   16               // 16 row-tiles of 64
#define TILE 64
#define NPAIRS 136            // NT*(NT+1)/2 unordered tile pairs
#define PART_ELEMS (NK * NT * B_SZ)   // 819200 floats
#define LOG2E 1.44269504088896340736f

// ---------------------------------------------------------------------------
// K1: fused GEMM + copy. grid 640 x 256. (Round-16 lesson: ledger says this
// kernel was ~15us at KS=2 = 1.5 blocks/CU = 1.5 waves/SIMD -> L2-latency
// bound. KS=4 doubles TLP; T traffic unchanged at 64 MB.)
//  blocks [0,512):   M = x@T scaled by log2e, SoA planes ws2[ks][c][row].
//                    rt = blk&127 (8 rows), ks = blk>>7 (128 f each).
//                    x block-uniform -> s_loads; T coalesced (256B/wave/f).
//  blocks [512,640): copy x rows into out (float2), 8 rows/block.
// ---------------------------------------------------------------------------
__global__ __launch_bounds__(256) void gemm_copy_kernel(const float* __restrict__ x,
                                                        const float* __restrict__ T,
                                                        float* __restrict__ ws2,
                                                        float* __restrict__ out,
                                                        int zero_feat) {
    const int t = threadIdx.x;

    if (blockIdx.x >= 512) {                 // ---- copy path
        const int b = blockIdx.x - 512;      // 0..127
#pragma unroll
        for (int r = 0; r < 8; ++r) {
            const int row = b * 8 + r;
            const float2* src = (const float2*)(x + (size_t)row * F_SZ);
            float2* dst = (float2*)(out + (size_t)row * OUTW);
            dst[t] = src[t];
            if (zero_feat && t < NK) out[(size_t)row * OUTW + F_SZ + t] = 0.0f;
        }
        return;
    }

    // ---- gemm path
    const int rt = blockIdx.x & 127;         // 8-row tile
    const int ks = blockIdx.x >> 7;          // k-split (0..3)
    if (t >= C_SZ) return;                   // no __syncthreads in this path
    const int r0 = rt * 8;
    const int f0 = ks * 128;

    float acc[8] = {0.f, 0.f, 0.f, 0.f, 0.f, 0.f, 0.f, 0.f};
    const float* xp = x + (size_t)r0 * F_SZ + f0;     // block-uniform base
    const float* Tp = T + (size_t)f0 * C_SZ + t;

#pragma unroll 8
    for (int f = 0; f < 128; ++f) {
        const float tv = Tp[(size_t)f * C_SZ];
#pragma unroll
        for (int r = 0; r < 8; ++r)
            acc[r] += xp[r * F_SZ + f] * tv;          // uniform -> s_load
    }

    float* dst = ws2 + ((size_t)(ks * C_SZ + t)) * B_SZ + r0;   // 32B aligned
    float4 lo = make_float4(acc[0] * LOG2E, acc[1] * LOG2E,
                            acc[2] * LOG2E, acc[3] * LOG2E);
    float4 hi = make_float4(acc[4] * LOG2E, acc[5] * LOG2E,
                            acc[6] * LOG2E, acc[7] * LOG2E);
    ((float4*)dst)[0] = lo;
    ((float4*)dst)[1] = hi;
}

// ---------------------------------------------------------------------------
// K2: symmetric pairwise features (round-9 version, byte-identical except the
// staging now sums KS=4 planes). grid 6800 = 50 k x 136 tile pairs (ti<=tj);
// 256 threads. Measured-best pair structure (35.7us total).
// ---------------------------------------------------------------------------
template <bool ATOMIC>
__global__ __launch_bounds__(256) void pair_kernel(const float* __restrict__ ws2,
                                                   float* __restrict__ part,
                                                   float* __restrict__ out) {
    // ---- decode block id -> (k, ti, tj), all scalar-uniform
    const int bid = blockIdx.x;
    const int k = bid / NPAIRS;
    int p = bid - k * NPAIRS;
    int ti = 0;
    while (p >= NT - ti) { p -= NT - ti; ++ti; }
    const int tj = ti + p;

    const int t    = threadIdx.x;
    const int lane = t & 63;
    const int jq   = t >> 6;

    __shared__ __align__(16) float qi[KD][TILE];
    __shared__ __align__(16) float qj[KD][TILE];
    __shared__ float et[TILE][TILE + 1];     // padded: b32 access both ways
    __shared__ float rowp[4][TILE];
    __shared__ float colp[4][TILE];

    const float* pk = ws2 + (size_t)k * (KD * B_SZ);  // plane 0, cols k*5..

    if (t < TILE) {                          // stage tile ti (coalesced SoA)
#pragma unroll
        for (int d = 0; d < KD; ++d) {
            const int row = ti * TILE + t;
            float v = 0.0f;
#pragma unroll
            for (int pl = 0; pl < KS; ++pl)
                v += pk[(size_t)pl * PLANE + d * B_SZ + row];
            qi[d][t] = v;
        }
    } else if (t < 2 * TILE) {               // stage tile tj
        const int l = t - TILE;
#pragma unroll
        for (int d = 0; d < KD; ++d) {
            const int row = tj * TILE + l;
            float v = 0.0f;
#pragma unroll
            for (int pl = 0; pl < KS; ++pl)
                v += pk[(size_t)pl * PLANE + d * B_SZ + row];
            qj[d][l] = v;
        }
    }
    __syncthreads();

    // ---- pass 1: 16 pairs/thread (i = lane, j = jq*16 + 0..15)
    float m0 = qi[0][lane], m1 = qi[1][lane], m2 = qi[2][lane],
          m3 = qi[3][lane], m4 = qi[4][lane];
    float acc = 0.0f;
#pragma unroll
    for (int c4 = 0; c4 < 4; ++c4) {
        const int j0 = jq * 16 + c4 * 4;
        const float4 c0 = *(const float4*)&qj[0][j0];   // broadcast b128
        const float4 c1 = *(const float4*)&qj[1][j0];
        const float4 c2 = *(const float4*)&qj[2][j0];
        const float4 c3 = *(const float4*)&qj[3][j0];
        const float4 c4_ = *(const float4*)&qj[4][j0];
#define PAIR_ONE(C, JOFF)                                                        \
        {                                                                        \
            const float s = __builtin_fabsf(m0 - c0.C)                           \
                          + __builtin_fabsf(m1 - c1.C)                           \
                          + __builtin_fabsf(m2 - c2.C)                           \
                          + __builtin_fabsf(m3 - c3.C)                           \
                          + __builtin_fabsf(m4 - c4_.C);                         \
            const float e = __builtin_amdgcn_exp2f(-s);                          \
            acc += e;                                                            \
            et[j0 + JOFF][lane] = e;                                             \
        }
        PAIR_ONE(x, 0) PAIR_ONE(y, 1) PAIR_ONE(z, 2) PAIR_ONE(w, 3)
#undef PAIR_ONE
    }
    rowp[jq][lane] = acc;
    __syncthreads();

    // ---- pass 2: column sums (rows of et), off-diagonal only
    if (ti != tj) {
        float csum = 0.0f;
#pragma unroll
        for (int e = 0; e < 16; ++e) csum += et[lane][jq * 16 + e];
        colp[jq][lane] = csum;
    }

    // ---- row partial: rows of tile ti, source tile tj
    if (t < TILE) {
        const float r = rowp[0][t] + rowp[1][t] + rowp[2][t] + rowp[3][t];
        const int row = ti * TILE + t;
        if (ATOMIC) atomicAdd(&out[(size_t)row * OUTW + F_SZ + k], r);
        else        part[((size_t)(k * NT + tj)) * B_SZ + row] = r;
    }

    // ---- col partial: rows of tile tj, source tile ti
    if (ti != tj) {
        __syncthreads();
        if (t < TILE) {
            const float c = colp[0][t] + colp[1][t] + colp[2][t] + colp[3][t];
            const int row = tj * TILE + t;
            if (ATOMIC) atomicAdd(&out[(size_t)row * OUTW + F_SZ + k], c);
            else        part[((size_t)(k * NT + ti)) * B_SZ + row] = c;
        }
    }
}

// ---------------------------------------------------------------------------
// K3: fold the 16 tile-source partials into out. grid 200 x 256.
// Reads coalesced (lanes contiguous in row); L2-resident.
// ---------------------------------------------------------------------------
__global__ __launch_bounds__(256) void reduce_kernel(const float* __restrict__ part,
                                                     float* __restrict__ out) {
    const int k = blockIdx.x >> 2;
    const int i = ((blockIdx.x & 3) << 8) | threadIdx.x;
    float s = 0.0f;
#pragma unroll
    for (int sp = 0; sp < NT; ++sp)
        s += part[((size_t)(k * NT + sp)) * B_SZ + i];
    out[(size_t)i * OUTW + F_SZ + k] = s;
}

// ---------------------------------------------------------------------------
extern "C" void kernel_launch(void* const* d_in, const int* in_sizes, int n_in,
                              void* d_out, int out_size, void* d_ws, size_t ws_size,
                              hipStream_t stream) {
    const float* x = (const float*)d_in[0];   // [1024, 512]
    const float* T = (const float*)d_in[1];   // [512, 250]
    float* out = (float*)d_out;               // [1024, 562]
    float* ws2 = (float*)d_ws;                // KS SoA planes [250][1024]
    float* part = ws2 + (size_t)KS * PLANE;   // [50][16][1024]

    const size_t need = ((size_t)KS * PLANE + PART_ELEMS) * 4;   // 7.4 MB
    const int fast = (ws_size >= need);

    gemm_copy_kernel<<<640, 256, 0, stream>>>(x, T, ws2, out, fast ? 0 : 1);

    if (fast) {
        pair_kernel<false><<<NK * NPAIRS, 256, 0, stream>>>(ws2, part, out);
        reduce_kernel<<<200, 256, 0, stream>>>(part, out);
    } else {
        pair_kernel<true><<<NK * NPAIRS, 256, 0, stream>>>(ws2, nullptr, out);
    }
}